// Round 12
// baseline (5756.683 us; speedup 1.0000x reference)
//
#include <hip/hip_runtime.h>
#include <hip/hip_bf16.h>

#define VOCAB 50000
#define EDIM 256
#define NF 128
#define KS 3
#define HID 128
#define NPATH 128
#define LSEQ 512
#define TCONV 510
#define TPOOL 509
#define CH 48   // LSTM chunk: gx(96KB) + x-f16(12KB) + g_l(2KB) + h_p(256B) ~= 110KB LDS

typedef unsigned int uint32;
typedef _Float16 h2 __attribute__((ext_vector_type(2)));

__device__ __forceinline__ float dot2(uint32 w, uint32 x, float acc) {
#if defined(__has_builtin) && __has_builtin(__builtin_amdgcn_fdot2)
  return __builtin_amdgcn_fdot2(__builtin_bit_cast(h2, w),
                                __builtin_bit_cast(h2, x), acc, false);
#else
  h2 a = __builtin_bit_cast(h2, w), b = __builtin_bit_cast(h2, x);
  return acc + (float)a[0] * (float)b[0] + (float)a[1] * (float)b[1];
#endif
}
__device__ __forceinline__ uint32 packf16(float a, float b) {
  h2 v;
  v[0] = (_Float16)a;
  v[1] = (_Float16)b;
  return __builtin_bit_cast(uint32, v);
}

__device__ __forceinline__ float sigf(float x) { return 1.f / (1.f + __expf(-x)); }
__device__ __forceinline__ float tanhf_(float x) {
  float e = __expf(2.f * x);
  return (e - 1.f) / (e + 1.f);
}

// ---------------------------------------------------------------- init:
// transpose conv weights to [e*3+k][f] for coalesced loads; u0 = emb_B[query]
__global__ void init_kernel(const float* __restrict__ conv_w,
                            const float* __restrict__ embB,
                            const int* __restrict__ query,
                            float* __restrict__ w_t, float* __restrict__ u_buf) {
  int idx = blockIdx.x * 256 + threadIdx.x;
  if (idx < EDIM * KS * NF) {
    int ek = idx >> 7, f = idx & (NF - 1);
    w_t[idx] = conv_w[f * (EDIM * KS) + ek];
  } else if (idx < EDIM * KS * NF + EDIM) {
    int i = idx - EDIM * KS * NF;
    u_buf[i] = embB[(size_t)query[0] * EDIM + i];
  }
}

// pack the 4 LSTM weight matrices (each [512][128] f32) into f16 pairs:
// wpack[m][row][c] = (src[row][2c], src[row][2c+1]),  m: ihF,hhF,ihB,hhB
__global__ __launch_bounds__(256) void pack_kernel(
    const float* __restrict__ w_ih_f, const float* __restrict__ w_hh_f,
    const float* __restrict__ w_ih_b, const float* __restrict__ w_hh_b,
    uint32* __restrict__ wpack) {
  int idx = blockIdx.x * 256 + threadIdx.x;  // 0 .. 131071
  int m = idx >> 15;
  int off = idx & 32767;
  const float* src = m == 0 ? w_ih_f : m == 1 ? w_hh_f : m == 2 ? w_ih_b : w_hh_b;
  wpack[idx] = packf16(src[2 * off], src[2 * off + 1]);
}

// ---------------------------------------------------------------- conv:
// fused embed gather + conv1d(K=3,VALID) + bias + relu + maxpool(2,stride1)
// block = (t-tile of 32 pooled outputs, path). 256 thr: f = tid&127, th = tid>>7.
__global__ __launch_bounds__(256) void conv_kernel(
    const int* __restrict__ path, const float* __restrict__ embA,
    const float* __restrict__ w_t, const float* __restrict__ conv_b,
    float* __restrict__ pooled) {
  __shared__ float xs[35 * EDIM];
  int t0 = blockIdx.x * 32;
  int p = blockIdx.y;
  const int* prow = path + p * LSEQ;
  for (int tok = 0; tok < 35; ++tok) {
    int tt = t0 + tok;
    float v = 0.f;
    if (tt < LSEQ) v = embA[(size_t)prow[tt] * EDIM + threadIdx.x];
    xs[tok * EDIM + threadIdx.x] = v;
  }
  __syncthreads();
  int f = threadIdx.x & (NF - 1), th = threadIdx.x >> 7;
  float b = conv_b[f];
  float acc[17];
#pragma unroll
  for (int i = 0; i < 17; ++i) acc[i] = b;
  for (int e = 0; e < EDIM; ++e) {
    float xv[19];
#pragma unroll
    for (int j = 0; j < 19; ++j) xv[j] = xs[(th * 16 + j) * EDIM + e];  // broadcast
#pragma unroll
    for (int k = 0; k < KS; ++k) {
      float wv = w_t[(e * KS + k) * NF + f];  // coalesced, L2-resident (393KB)
#pragma unroll
      for (int i = 0; i < 17; ++i) acc[i] += wv * xv[i + k];
    }
  }
#pragma unroll
  for (int i = 0; i < 16; ++i) {
    int t = t0 + th * 16 + i;
    if (t < TPOOL) {
      float v = fmaxf(fmaxf(acc[i], 0.f), fmaxf(acc[i + 1], 0.f));
      pooled[((size_t)p * TPOOL + t) * NF + f] = v;
    }
  }
}

// ---------------------------------------------------------------- lstm:
// one block per (path, direction), 512 thr.  r11 evidence: scratch gone
// (FETCH 36MB), but phase 2 was issue-bound: ~400 VALU inst/step (256 FMA +
// 128 bf16-unpack).  This version: f16-packed weights + v_dot2_f32_f16 ->
// ~90 inst/step (64 dot2, no unpack), phase 1 dot2 too (half loads, half FMA).
//  - ONLY w_hh register-resident (64 packed regs, loaded once, grouped).
//  - phase 1: gx = bias + x @ w_ih^T into LDS, (4 gates x 4 steps) tile,
//    w_ih-f16 streamed from L2.
//  - phase 2: per step, gate tid: 16 ds_read_b128 (h packed, broadcast) +
//    64 dot2; h-update by tid<128, f16-pack via intra-wave shfl.
__global__ __launch_bounds__(512, 1) void lstm_kernel(
    const float* __restrict__ pooled, const uint32* __restrict__ wpack,
    const float* __restrict__ b_ih_f, const float* __restrict__ b_hh_f,
    const float* __restrict__ b_ih_b, const float* __restrict__ b_hh_b,
    float* __restrict__ context) {
  __shared__ __align__(16) uint32 x_l[CH][NF / 2];   // 12 KB, f16-packed x
  __shared__ __align__(16) float gx_l[CH][4 * HID];  // 96 KB
  __shared__ __align__(16) uint32 h_p[HID / 2];      // 256 B, f16-packed h
  __shared__ float g_l[4 * HID];
  int p = blockIdx.x >> 1, d = blockIdx.x & 1;
  const uint32* wihp = wpack + (d ? 2 : 0) * 32768;
  const uint32* whhp = wpack + (d ? 3 : 1) * 32768;
  const float* b_ih = d ? b_ih_b : b_ih_f;
  const float* b_hh = d ? b_hh_b : b_hh_f;
  int tid = threadIdx.x;
  int gq = tid & 127, jq = tid >> 7;

  // persistent packed w_hh row for gate `tid`: 64 uint32, single load site,
  // grouped to cap in-flight transient registers.
  uint32 whh[64];
#pragma unroll
  for (int grp = 0; grp < 4; ++grp) {
#pragma unroll
    for (int q = 0; q < 4; ++q) {
      int jj = grp * 4 + q;
      uint4 t = *(const uint4*)(whhp + (size_t)tid * 64 + 4 * jj);
      whh[4 * jj] = t.x;
      whh[4 * jj + 1] = t.y;
      whh[4 * jj + 2] = t.z;
      whh[4 * jj + 3] = t.w;
    }
    __builtin_amdgcn_sched_barrier(0);
  }
  float bias4[4];
#pragma unroll
  for (int gi = 0; gi < 4; ++gi)
    bias4[gi] = b_ih[4 * gq + gi] + b_hh[4 * gq + gi];

  float c = 0.f, h = 0.f;
  if (tid < HID / 2) h_p[tid] = 0u;
  const float* prow = pooled + (size_t)p * TPOOL * NF;

  for (int t0 = 0; t0 < TPOOL; t0 += CH) {
    int ns = (TPOOL - t0 < CH) ? (TPOOL - t0) : CH;
    // ---- stage x chunk, converting f32 -> packed f16 (8 elems / item)
    for (int q = tid; q < ns * 16; q += 512) {
      int j = q >> 4, b = q & 15;
      int ti = d ? (TPOOL - 1 - (t0 + j)) : (t0 + j);
      const float* s = prow + ti * NF + b * 8;
      float4 u = *(const float4*)s, v = *(const float4*)(s + 4);
      x_l[j][4 * b] = packf16(u.x, u.y);
      x_l[j][4 * b + 1] = packf16(u.z, u.w);
      x_l[j][4 * b + 2] = packf16(v.x, v.y);
      x_l[j][4 * b + 3] = packf16(v.z, v.w);
    }
    __syncthreads();  // x_l ready (prev chunk fully done: step-loop barriers)
    // ---- phase 1: gx tile (4 gates x 4 steps), packed w_ih streamed from L2
    const uint32* wbase = wihp + (size_t)(4 * gq) * 64;
    for (int ps = 0; ps < 3; ++ps) {
      int jb = jq * 12 + ps * 4;
      float acc[4][4];
#pragma unroll
      for (int ji = 0; ji < 4; ++ji)
#pragma unroll
        for (int gi = 0; gi < 4; ++gi) acc[ji][gi] = bias4[gi];
      for (int jj = 0; jj < 16; ++jj) {  // runtime loop: caps reg pressure
        uint4 w0 = *(const uint4*)(wbase + 0 * 64 + 4 * jj);
        uint4 w1 = *(const uint4*)(wbase + 1 * 64 + 4 * jj);
        uint4 w2 = *(const uint4*)(wbase + 2 * 64 + 4 * jj);
        uint4 w3 = *(const uint4*)(wbase + 3 * 64 + 4 * jj);
#pragma unroll
        for (int ji = 0; ji < 4; ++ji) {
          uint4 xv = *(const uint4*)&x_l[jb + ji][4 * jj];  // LDS broadcast
          acc[ji][0] = dot2(w0.w, xv.w, dot2(w0.z, xv.z, dot2(w0.y, xv.y, dot2(w0.x, xv.x, acc[ji][0]))));
          acc[ji][1] = dot2(w1.w, xv.w, dot2(w1.z, xv.z, dot2(w1.y, xv.y, dot2(w1.x, xv.x, acc[ji][1]))));
          acc[ji][2] = dot2(w2.w, xv.w, dot2(w2.z, xv.z, dot2(w2.y, xv.y, dot2(w2.x, xv.x, acc[ji][2]))));
          acc[ji][3] = dot2(w3.w, xv.w, dot2(w3.z, xv.z, dot2(w3.y, xv.y, dot2(w3.x, xv.x, acc[ji][3]))));
        }
      }
#pragma unroll
      for (int ji = 0; ji < 4; ++ji)
        if (jb + ji < ns)
          *(float4*)&gx_l[jb + ji][4 * gq] =
              make_float4(acc[ji][0], acc[ji][1], acc[ji][2], acc[ji][3]);
    }
    __syncthreads();  // gx complete
    // ---- phase 2: recurrence (h-dot only, packed)
    for (int j = 0; j < ns; ++j) {
      float a0 = gx_l[j][tid], a1 = 0.f, a2 = 0.f, a3 = 0.f;
#pragma unroll
      for (int jj = 0; jj < 16; ++jj) {
        uint4 hv = *(const uint4*)&h_p[4 * jj];  // broadcast read
        a0 = dot2(whh[4 * jj], hv.x, a0);
        a1 = dot2(whh[4 * jj + 1], hv.y, a1);
        a2 = dot2(whh[4 * jj + 2], hv.z, a2);
        a3 = dot2(whh[4 * jj + 3], hv.w, a3);
      }
      g_l[tid] = (a0 + a1) + (a2 + a3);
      __syncthreads();  // gates complete
      if (tid < HID) {
        float gi = g_l[tid], gf = g_l[HID + tid], gg = g_l[2 * HID + tid],
              go = g_l[3 * HID + tid];
        c = sigf(gf) * c + sigf(gi) * tanhf_(gg);
        h = sigf(go) * tanhf_(c);
        float hn = __shfl_down(h, 1, 64);  // pair partner (tid, tid+1) same wave
        if (!(tid & 1)) h_p[tid >> 1] = packf16(h, hn);
      }
      __syncthreads();  // h_p ready for next step
    }
  }
  if (tid < HID) context[p * 2 * HID + d * HID + tid] = h;
}

// ---------------------------------------------------------------- attention
__global__ __launch_bounds__(256) void score_kernel(
    const float* __restrict__ context, const float* __restrict__ u_buf,
    const float* __restrict__ d1_w, const float* __restrict__ d1_b,
    const float* __restrict__ d2_w, const float* __restrict__ d2_b,
    float* __restrict__ scores) {
  __shared__ __align__(16) float cat[2 * EDIM];
  __shared__ float red[4];
  int p = blockIdx.x;
  int i = threadIdx.x;
  cat[i] = context[p * 2 * HID + i];
  cat[EDIM + i] = u_buf[i];
  __syncthreads();
  float acc = d1_b[i];
  const float4* wrow = (const float4*)(d1_w + (size_t)i * 2 * EDIM);
#pragma unroll 8
  for (int j = 0; j < 128; ++j) {
    float4 w4 = wrow[j];
    float4 c4 = *(const float4*)(&cat[4 * j]);
    acc += w4.x * c4.x + w4.y * c4.y + w4.z * c4.z + w4.w * c4.w;
  }
  float v = tanhf_(acc) * d2_w[i];
#pragma unroll
  for (int o = 32; o; o >>= 1) v += __shfl_down(v, o, 64);
  int lane = i & 63, w = i >> 6;
  if (lane == 0) red[w] = v;
  __syncthreads();
  if (i == 0) scores[p] = red[0] + red[1] + red[2] + red[3] + d2_b[0];
}

__global__ __launch_bounds__(256) void reduce_kernel(
    const float* __restrict__ context, const float* __restrict__ d1_w,
    const float* __restrict__ d1_b, const float* __restrict__ d2_w,
    const float* __restrict__ d2_b, const float* __restrict__ scores,
    float* __restrict__ u_buf, float* __restrict__ out, int final_step) {
  __shared__ float al[NPATH];
  __shared__ __align__(16) float uo[2 * EDIM];
  __shared__ float red[4];
  int i = threadIdx.x;
  int lane = i & 63, w = i >> 6;

  // softmax over 128 path scores
  float s = (i < NPATH) ? scores[i] : -1e30f;
  float m = s;
#pragma unroll
  for (int o = 32; o; o >>= 1) m = fmaxf(m, __shfl_down(m, o, 64));
  if (lane == 0) red[w] = m;
  __syncthreads();
  m = fmaxf(fmaxf(red[0], red[1]), fmaxf(red[2], red[3]));
  __syncthreads();
  float e = (i < NPATH) ? __expf(s - m) : 0.f;
  float t = e;
#pragma unroll
  for (int o = 32; o; o >>= 1) t += __shfl_down(t, o, 64);
  if (lane == 0) red[w] = t;
  __syncthreads();
  float sum = red[0] + red[1] + red[2] + red[3];
  if (i < NPATH) al[i] = e / sum;
  __syncthreads();

  // o = sum_p alpha[p] * context[p]  (i in 0..255)
  float o_i = 0.f;
  for (int p = 0; p < NPATH; ++p) o_i += al[p] * context[p * 2 * HID + i];
  uo[i] = u_buf[i];
  uo[EDIM + i] = o_i;
  __syncthreads();

  // u_new = [u;o] @ d1_w.T + d1_b
  float un = d1_b[i];
  const float4* wrow = (const float4*)(d1_w + (size_t)i * 2 * EDIM);
#pragma unroll 8
  for (int j = 0; j < 128; ++j) {
    float4 w4 = wrow[j];
    float4 c4 = *(const float4*)(&uo[4 * j]);
    un += w4.x * c4.x + w4.y * c4.y + w4.z * c4.z + w4.w * c4.w;
  }
  if (!final_step) {
    u_buf[i] = un;
  } else {
    float v = fmaxf(un, 0.f) * d2_w[i];
#pragma unroll
    for (int o = 32; o; o >>= 1) v += __shfl_down(v, o, 64);
    if (lane == 0) red[w] = v;
    __syncthreads();
    if (i == 0) {
      float tot = red[0] + red[1] + red[2] + red[3] + d2_b[0];
      out[0] = 1.f / (1.f + __expf(-tot));
    }
  }
}

// ----------------------------------------------------------------
extern "C" void kernel_launch(void* const* d_in, const int* in_sizes, int n_in,
                              void* d_out, int out_size, void* d_ws, size_t ws_size,
                              hipStream_t stream) {
  const int* path = (const int*)d_in[0];
  const int* query = (const int*)d_in[1];
  const float* embA = (const float*)d_in[2];
  const float* embB = (const float*)d_in[3];
  const float* conv_w = (const float*)d_in[4];
  const float* conv_b = (const float*)d_in[5];
  const float* w_ih_f = (const float*)d_in[6];
  const float* w_hh_f = (const float*)d_in[7];
  const float* b_ih_f = (const float*)d_in[8];
  const float* b_hh_f = (const float*)d_in[9];
  const float* w_ih_b = (const float*)d_in[10];
  const float* w_hh_b = (const float*)d_in[11];
  const float* b_ih_b = (const float*)d_in[12];
  const float* b_hh_b = (const float*)d_in[13];
  const float* d1_w = (const float*)d_in[14];
  const float* d1_b = (const float*)d_in[15];
  const float* d2_w = (const float*)d_in[16];
  const float* d2_b = (const float*)d_in[17];
  float* out = (float*)d_out;

  float* ws = (float*)d_ws;
  float* pooled = ws;                                     // 128*509*128
  float* w_t = pooled + (size_t)NPATH * TPOOL * NF;       // 768*128
  float* context = w_t + EDIM * KS * NF;                  // 128*256
  float* scores = context + NPATH * 2 * HID;              // 128
  float* u_buf = scores + NPATH;                          // 256
  uint32* wpack = (uint32*)(u_buf + EDIM);                // 4*512*64 uint32 (512KB)

  init_kernel<<<(EDIM * KS * NF + EDIM + 255) / 256, 256, 0, stream>>>(
      conv_w, embB, query, w_t, u_buf);
  pack_kernel<<<512, 256, 0, stream>>>(w_ih_f, w_hh_f, w_ih_b, w_hh_b, wpack);
  conv_kernel<<<dim3(16, NPATH), 256, 0, stream>>>(path, embA, w_t, conv_b,
                                                   pooled);
  lstm_kernel<<<256, 512, 0, stream>>>(pooled, wpack, b_ih_f, b_hh_f, b_ih_b,
                                       b_hh_b, context);
  score_kernel<<<NPATH, 256, 0, stream>>>(context, u_buf, d1_w, d1_b, d2_w,
                                          d2_b, scores);
  reduce_kernel<<<1, 256, 0, stream>>>(context, d1_w, d1_b, d2_w, d2_b, scores,
                                       u_buf, out, 0);
  score_kernel<<<NPATH, 256, 0, stream>>>(context, u_buf, d1_w, d1_b, d2_w,
                                          d2_b, scores);
  reduce_kernel<<<1, 256, 0, stream>>>(context, d1_w, d1_b, d2_w, d2_b, scores,
                                       u_buf, out, 1);
}